// Round 8
// baseline (119.273 us; speedup 1.0000x reference)
//
#include <hip/hip_runtime.h>
#include <hip/hip_fp16.h>
#include <cstdint>

#define NT      32768
#define DIN     256
#define DHID    1024
#define DOUT    256
#define NPLANES 8
#define NBLK    (NT / 256)

typedef unsigned short u16;
typedef __attribute__((ext_vector_type(8))) _Float16 f16x8;
typedef __attribute__((ext_vector_type(4))) float    f32x4;

// ---------------- workspace layout (bytes) ----------------
#define WS_OFFSETS 0                           // 9 ints
#define WS_META    64                          // 1 int (ntiles, 128-row granularity)
#define WS_TP      1024                        // <=264 ints
#define WS_TM      (WS_TP + 544*4)
#define WS_BLKHIST (WS_TM + 544*4)
#define WS_BLKBASE (WS_BLKHIST + NBLK*8*4)
#define WS_PERM    (WS_BLKBASE + NBLK*8*4)
#define WS_XB      (WS_PERM + NT*4)            // NT*DIN f16, natural order
#define WS_W1B     (WS_XB + NT*DIN*2)
#define WS_W2B     (WS_W1B + NPLANES*DHID*DIN*2)
#define WS_HB      (WS_W2B + NPLANES*DOUT*DHID*2)   // NT*DHID f16, bucketed

__device__ __forceinline__ u16 f2h_bits(float f) {
    __half h = __float2half(f);
    return *reinterpret_cast<u16*>(&h);
}

__device__ __forceinline__ void gl_lds16(const void* g, void* l) {
    __builtin_amdgcn_global_load_lds(
        (const __attribute__((address_space(1))) void*)g,
        (__attribute__((address_space(3))) void*)l,
        16, 0, 0);
}

// fast gelu: tanh-form, |dev vs exact erf-gelu| <~ 5e-4 (negligible after W2)
__device__ __forceinline__ float gelu_fast(float x) {
    const float u = x * (1.5957691216f + 0.07135481283f * x * x);
    const float e = __expf(-u);
    return x * __builtin_amdgcn_rcpf(1.0f + e);
}

// ---------------- fused prologue: per-block hist + f32->f16 converts ----------
__global__ void prep_k(const int* __restrict__ pidx, const float* __restrict__ x,
                       const float* __restrict__ W1, const float* __restrict__ W2,
                       int* __restrict__ blkhist, u16* __restrict__ xb,
                       u16* __restrict__ w1b, u16* __restrict__ w2b) {
    __shared__ int cnt[NPLANES];
    const int t = threadIdx.x, lane = t & 63;
    if ((int)blockIdx.x < NBLK) {
        if (t < NPLANES) cnt[t] = 0;
        __syncthreads();
        const int p = pidx[blockIdx.x * 256 + t];
#pragma unroll
        for (int q = 0; q < NPLANES; ++q) {
            unsigned long long m = __ballot(p == q);
            if (p == q && __popcll(m & ((1ULL << lane) - 1)) == 0)
                atomicAdd(&cnt[q], __popcll(m));
        }
        __syncthreads();
        if (t < NPLANES) blkhist[blockIdx.x * NPLANES + t] = cnt[t];
    }
    const int n0 = NT * DIN / 4, n1 = NPLANES * DHID * DIN / 4, n2 = NPLANES * DOUT * DHID / 4;
    const int stride = gridDim.x * blockDim.x;
    for (int i = blockIdx.x * blockDim.x + t; i < n0 + n1 + n2; i += stride) {
        const float4* s; ushort4* d; int j;
        if (i < n0)           { s = (const float4*)x;  d = (ushort4*)xb;  j = i; }
        else if (i < n0 + n1) { s = (const float4*)W1; d = (ushort4*)w1b; j = i - n0; }
        else                  { s = (const float4*)W2; d = (ushort4*)w2b; j = i - n0 - n1; }
        float4 v = s[j];
        ushort4 o;
        o.x = f2h_bits(v.x); o.y = f2h_bits(v.y);
        o.z = f2h_bits(v.z); o.w = f2h_bits(v.w);
        d[j] = o;
    }
}

// ---------------- scan: offsets + 128-row tile list + per-block bases --------
__global__ void scan_k(const int* __restrict__ blkhist, int* __restrict__ offsets,
                       int* __restrict__ blkbase, int* __restrict__ meta,
                       int* __restrict__ tp, int* __restrict__ tm) {
    __shared__ int tot[NPLANES];
    const int t = threadIdx.x;
    if (t < NPLANES) {
        int s = 0;
#pragma unroll 8
        for (int b = 0; b < NBLK; ++b) s += blkhist[b * NPLANES + t];
        tot[t] = s;
    }
    __syncthreads();
    if (t == 0) {
        int off = 0, tc = 0;
        for (int p = 0; p < NPLANES; ++p) {
            offsets[p] = off;
            for (int m = 0; m < tot[p]; m += 128) { tp[tc] = p; tm[tc] = m; ++tc; }
            off += tot[p];
        }
        offsets[NPLANES] = off;
        meta[0] = tc;
    }
    __syncthreads();
    if (t < NPLANES) {
        int run = offsets[t];
#pragma unroll 8
        for (int b = 0; b < NBLK; ++b) {
            blkbase[b * NPLANES + t] = run;
            run += blkhist[b * NPLANES + t];
        }
    }
}

__global__ void scatter_k(const int* __restrict__ pidx, const int* __restrict__ blkbase,
                          int* __restrict__ perm) {
    __shared__ int wcnt[4][NPLANES];
    __shared__ int wbase[4][NPLANES];
    const int t = threadIdx.x, lane = t & 63, wave = t >> 6;
    const int i = blockIdx.x * 256 + t;
    const int p = pidx[i];
    int rank = 0;
#pragma unroll
    for (int q = 0; q < NPLANES; ++q) {
        unsigned long long m = __ballot(p == q);
        if (lane == 0) wcnt[wave][q] = __popcll(m);
        if (p == q) rank = __popcll(m & ((1ULL << lane) - 1));
    }
    __syncthreads();
    if (t < NPLANES) {
        int run = blkbase[blockIdx.x * NPLANES + t];
#pragma unroll
        for (int w = 0; w < 4; ++w) { wbase[w][t] = run; run += wcnt[w][t]; }
    }
    __syncthreads();
    perm[wbase[wave][p] + rank] = i;
}

// XCD-chunked tile mapping: all NSPLIT n-blocks of a tile on ONE XCD,
// tiles chunked contiguously per XCD (m204 bijective) so W[p] stays L2-hot.
// VERIFIED R6: HW round-robin XCD = linear_block_id % 8 (FETCH 68.6->11.1 MB).
#define XCD_MAP(NSPLIT)                                                        \
    const int ntiles = meta[0];                                                \
    const int xcd = blockIdx.x & 7, idx = blockIdx.x >> 3;                     \
    const int q8 = ntiles >> 3, r8 = ntiles & 7;                               \
    const int tn = q8 + (xcd < r8 ? 1 : 0);                                    \
    if (idx >= tn * (NSPLIT)) return;                                          \
    const int tile = (xcd < r8 ? xcd * (q8 + 1)                                \
                               : r8 * (q8 + 1) + (xcd - r8) * q8)              \
                     + idx / (NSPLIT);                                         \
    const int n0v = (idx % (NSPLIT)) * 128;

// ---------------- gemm1: 128x128 m97 tile, A via perm, LDS-staged gelu epilogue
__global__ __launch_bounds__(256, 3) void gemm1_k(
    const u16* __restrict__ xb, const u16* __restrict__ w1b,
    const float* __restrict__ b1, const int* __restrict__ perm,
    const int* __restrict__ offsets, const int* __restrict__ meta,
    const int* __restrict__ tp, const int* __restrict__ tm,
    u16* __restrict__ hb)
{
    __shared__ __align__(16) u16 smem[16384];   // sA 16KB | sB 16KB; sOut 32KB reuse
    XCD_MAP(8)
    const int p   = tp[tile];
    const int m0  = tm[tile];
    const int off = offsets[p];
    const int cnt = offsets[p + 1] - off;

    u16* const sA = smem;
    u16* const sB = smem + 8192;

    const int tid = threadIdx.x, srow = tid >> 3, sch = tid & 7;
    const u16* aptr[4];
    const u16* bptr[4];
#pragma unroll
    for (int i = 0; i < 4; ++i) {
        const int r  = i * 32 + srow;
        const int gr = min(m0 + r, cnt - 1);
        aptr[i] = xb + (size_t)perm[off + gr] * DIN + ((sch ^ (r & 7)) * 8);
        bptr[i] = w1b + ((size_t)p * DHID + n0v + r) * DIN + ((sch ^ (r & 7)) * 8);
    }
    const int wave = tid >> 6, lane = tid & 63;
    const int wm = (wave >> 1) * 64, wn = (wave & 1) * 64;
    const int lm = lane & 15, lk = lane >> 4;

    f32x4 acc[4][4];
#pragma unroll
    for (int a = 0; a < 4; ++a)
#pragma unroll
        for (int b = 0; b < 4; ++b) acc[a][b] = (f32x4){0.f, 0.f, 0.f, 0.f};

    for (int kt = 0; kt < DIN / 64; ++kt) {
        const int k0 = kt * 64;
#pragma unroll
        for (int i = 0; i < 4; ++i) {
            gl_lds16(aptr[i] + k0, sA + i * 2048 + tid * 8);
            gl_lds16(bptr[i] + k0, sB + i * 2048 + tid * 8);
        }
        __syncthreads();
#pragma unroll
        for (int kk = 0; kk < 2; ++kk) {
            f16x8 af[4], bf[4];
#pragma unroll
            for (int mf = 0; mf < 4; ++mf) {
                const int row = wm + mf * 16 + lm;
                const int g   = kk * 4 + lk;
                af[mf] = *(const f16x8*)(sA + row * 64 + ((g ^ (row & 7)) * 8));
            }
#pragma unroll
            for (int nf = 0; nf < 4; ++nf) {
                const int row = wn + nf * 16 + lm;
                const int g   = kk * 4 + lk;
                bf[nf] = *(const f16x8*)(sB + row * 64 + ((g ^ (row & 7)) * 8));
            }
#pragma unroll
            for (int mf = 0; mf < 4; ++mf)
#pragma unroll
                for (int nf = 0; nf < 4; ++nf)
                    acc[mf][nf] = __builtin_amdgcn_mfma_f32_16x16x32_f16(
                        af[mf], bf[nf], acc[mf][nf], 0, 0, 0);
        }
        __syncthreads();
    }

    // ---- epilogue: fast gelu -> chunk-swizzled sOut (32KB), coalesced copy-out
    u16* const sOut = smem;                     // 128 x 128 u16
#pragma unroll
    for (int nf = 0; nf < 4; ++nf) {
        const int col = wn + nf * 16 + lm;      // 0..127 within tile
        const float bb = b1[p * DHID + n0v + col];
        const int cc = col >> 3, c7 = col & 7;
#pragma unroll
        for (int mf = 0; mf < 4; ++mf) {
#pragma unroll
            for (int j = 0; j < 4; ++j) {
                const int tok = wm + mf * 16 + lk * 4 + j;
                sOut[tok * 128 + ((cc ^ (tok & 15)) * 8) + c7] =
                    f2h_bits(gelu_fast(acc[mf][nf][j] + bb));
            }
        }
    }
    __syncthreads();
    const int r = tid >> 1, hh = tid & 1;       // 2 threads/row, 128B each
    if (m0 + r < cnt) {
        u16* dst = hb + (size_t)(off + m0 + r) * DHID + n0v;
#pragma unroll
        for (int c = 0; c < 8; ++c) {
            const int l = hh * 8 + c;
            *(int4*)(dst + l * 8) = *(const int4*)(sOut + r * 128 + ((l ^ (r & 15)) * 8));
        }
    }
}

// ---------------- gemm2: 128x128 m97 tile, single-buffer, f32 scatter epilogue
__global__ __launch_bounds__(256, 3) void gemm2_k(
    const u16* __restrict__ hb, const u16* __restrict__ w2b,
    const float* __restrict__ b2, const int* __restrict__ perm,
    const int* __restrict__ offsets, const int* __restrict__ meta,
    const int* __restrict__ tp, const int* __restrict__ tm,
    float* __restrict__ out)
{
    __shared__ __align__(16) u16 smem[16384];   // sA 16KB | sB 16KB
    XCD_MAP(2)
    const int p   = tp[tile];
    const int m0  = tm[tile];
    const int off = offsets[p];
    const int cnt = offsets[p + 1] - off;

    u16* const sA = smem;
    u16* const sB = smem + 8192;

    const int tid = threadIdx.x, srow = tid >> 3, sch = tid & 7;
    const u16* aptr[4];
    const u16* bptr[4];
#pragma unroll
    for (int i = 0; i < 4; ++i) {
        const int r  = i * 32 + srow;
        const int gr = min(m0 + r, cnt - 1);
        aptr[i] = hb + (size_t)(off + gr) * DHID + ((sch ^ (r & 7)) * 8);
        bptr[i] = w2b + ((size_t)p * DOUT + n0v + r) * DHID + ((sch ^ (r & 7)) * 8);
    }
    const int wave = tid >> 6, lane = tid & 63;
    const int wm = (wave >> 1) * 64, wn = (wave & 1) * 64;
    const int lm = lane & 15, lk = lane >> 4;

    f32x4 acc[4][4];
#pragma unroll
    for (int a = 0; a < 4; ++a)
#pragma unroll
        for (int b = 0; b < 4; ++b) acc[a][b] = (f32x4){0.f, 0.f, 0.f, 0.f};

    for (int kt = 0; kt < DHID / 64; ++kt) {
        const int k0 = kt * 64;
#pragma unroll
        for (int i = 0; i < 4; ++i) {
            gl_lds16(aptr[i] + k0, sA + i * 2048 + tid * 8);
            gl_lds16(bptr[i] + k0, sB + i * 2048 + tid * 8);
        }
        __syncthreads();
#pragma unroll
        for (int kk = 0; kk < 2; ++kk) {
            f16x8 af[4], bf[4];
#pragma unroll
            for (int mf = 0; mf < 4; ++mf) {
                const int row = wm + mf * 16 + lm;
                const int g   = kk * 4 + lk;
                af[mf] = *(const f16x8*)(sA + row * 64 + ((g ^ (row & 7)) * 8));
            }
#pragma unroll
            for (int nf = 0; nf < 4; ++nf) {
                const int row = wn + nf * 16 + lm;
                const int g   = kk * 4 + lk;
                bf[nf] = *(const f16x8*)(sB + row * 64 + ((g ^ (row & 7)) * 8));
            }
#pragma unroll
            for (int mf = 0; mf < 4; ++mf)
#pragma unroll
                for (int nf = 0; nf < 4; ++nf)
                    acc[mf][nf] = __builtin_amdgcn_mfma_f32_16x16x32_f16(
                        af[mf], bf[nf], acc[mf][nf], 0, 0, 0);
        }
        __syncthreads();
    }

    // epilogue: f32 scatter, 64B runs per 16-lane group
#pragma unroll
    for (int nf = 0; nf < 4; ++nf) {
        const int col = n0v + wn + nf * 16 + lm;
        const float bb = b2[p * DOUT + col];
#pragma unroll
        for (int mf = 0; mf < 4; ++mf) {
#pragma unroll
            for (int j = 0; j < 4; ++j) {
                const int tok = wm + mf * 16 + lk * 4 + j;
                if (m0 + tok < cnt)
                    out[(size_t)perm[off + m0 + tok] * DOUT + col] = acc[mf][nf][j] + bb;
            }
        }
    }
}

// ---------------- launch ----------------
extern "C" void kernel_launch(void* const* d_in, const int* in_sizes, int n_in,
                              void* d_out, int out_size, void* d_ws, size_t ws_size,
                              hipStream_t stream) {
    const float* x    = (const float*)d_in[0];
    const float* W1   = (const float*)d_in[1];
    const float* b1   = (const float*)d_in[2];
    const float* W2   = (const float*)d_in[3];
    const float* b2   = (const float*)d_in[4];
    const int*   pidx = (const int*)d_in[5];
    float*       out  = (float*)d_out;

    char* ws      = (char*)d_ws;
    int* offsets  = (int*)(ws + WS_OFFSETS);
    int* meta     = (int*)(ws + WS_META);
    int* tp       = (int*)(ws + WS_TP);
    int* tm       = (int*)(ws + WS_TM);
    int* blkhist  = (int*)(ws + WS_BLKHIST);
    int* blkbase  = (int*)(ws + WS_BLKBASE);
    int* perm     = (int*)(ws + WS_PERM);
    u16* xb       = (u16*)(ws + WS_XB);
    u16* w1b      = (u16*)(ws + WS_W1B);
    u16* w2b      = (u16*)(ws + WS_W2B);
    u16* hb       = (u16*)(ws + WS_HB);

    prep_k<<<2048, 256, 0, stream>>>(pidx, x, W1, W2, blkhist, xb, w1b, w2b);
    scan_k<<<1, 64, 0, stream>>>(blkhist, offsets, blkbase, meta, tp, tm);
    scatter_k<<<NBLK, 256, 0, stream>>>(pidx, blkbase, perm);

    // ntiles(128-gran) <= 264 -> <=34 tiles/xcd
    // gemm1: 8 n-blocks/tile -> 8 xcd * 34 * 8 = 2176 slots
    gemm1_k<<<2176, 256, 0, stream>>>(xb, w1b, b1, perm, offsets, meta, tp, tm, hb);
    // gemm2: 2 n-blocks/tile -> 8 * 34 * 2 = 544 slots
    gemm2_k<<<544, 256, 0, stream>>>(hb, w2b, b2, perm, offsets, meta, tp, tm, out);
}

// Round 9
// 114.723 us; speedup vs baseline: 1.0397x; 1.0397x over previous
//
#include <hip/hip_runtime.h>
#include <hip/hip_fp16.h>
#include <cstdint>

#define NT      32768
#define DIN     256
#define DHID    1024
#define DOUT    256
#define NPLANES 8
#define NBLK    (NT / 256)

typedef unsigned short u16;
typedef __attribute__((ext_vector_type(8))) _Float16 f16x8;
typedef __attribute__((ext_vector_type(4))) float    f32x4;

// ---------------- workspace layout (bytes) ----------------
#define WS_OFFSETS 0                           // 9 ints
#define WS_META    64                          // 1 int (ntiles, 64-row granularity)
#define WS_TP      1024                        // 544 ints
#define WS_TM      (WS_TP + 544*4)
#define WS_BLKHIST (WS_TM + 544*4)
#define WS_BLKBASE (WS_BLKHIST + NBLK*8*4)
#define WS_PERM    (WS_BLKBASE + NBLK*8*4)
#define WS_XB      (WS_PERM + NT*4)            // NT*DIN f16, natural order
#define WS_W1B     (WS_XB + NT*DIN*2)
#define WS_W2B     (WS_W1B + NPLANES*DHID*DIN*2)
#define WS_HB      (WS_W2B + NPLANES*DOUT*DHID*2)   // NT*DHID f16, bucketed

__device__ __forceinline__ u16 f2h_bits(float f) {
    __half h = __float2half(f);
    return *reinterpret_cast<u16*>(&h);
}

__device__ __forceinline__ void gl_lds16(const void* g, void* l) {
    __builtin_amdgcn_global_load_lds(
        (const __attribute__((address_space(1))) void*)g,
        (__attribute__((address_space(3))) void*)l,
        16, 0, 0);
}

// fast gelu: tanh-form, |dev vs exact erf-gelu| <~ 5e-4 (negligible after W2)
__device__ __forceinline__ float gelu_fast(float x) {
    const float u = x * (1.5957691216f + 0.07135481283f * x * x);
    const float e = __expf(-u);
    return x * __builtin_amdgcn_rcpf(1.0f + e);
}

// ---------------- fused prologue: per-block hist + f32->f16 converts ----------
__global__ void prep_k(const int* __restrict__ pidx, const float* __restrict__ x,
                       const float* __restrict__ W1, const float* __restrict__ W2,
                       int* __restrict__ blkhist, u16* __restrict__ xb,
                       u16* __restrict__ w1b, u16* __restrict__ w2b) {
    __shared__ int cnt[NPLANES];
    const int t = threadIdx.x, lane = t & 63;
    if ((int)blockIdx.x < NBLK) {
        if (t < NPLANES) cnt[t] = 0;
        __syncthreads();
        const int p = pidx[blockIdx.x * 256 + t];
#pragma unroll
        for (int q = 0; q < NPLANES; ++q) {
            unsigned long long m = __ballot(p == q);
            if (p == q && __popcll(m & ((1ULL << lane) - 1)) == 0)
                atomicAdd(&cnt[q], __popcll(m));
        }
        __syncthreads();
        if (t < NPLANES) blkhist[blockIdx.x * NPLANES + t] = cnt[t];
    }
    const int n0 = NT * DIN / 4, n1 = NPLANES * DHID * DIN / 4, n2 = NPLANES * DOUT * DHID / 4;
    const int stride = gridDim.x * blockDim.x;
    for (int i = blockIdx.x * blockDim.x + t; i < n0 + n1 + n2; i += stride) {
        const float4* s; ushort4* d; int j;
        if (i < n0)           { s = (const float4*)x;  d = (ushort4*)xb;  j = i; }
        else if (i < n0 + n1) { s = (const float4*)W1; d = (ushort4*)w1b; j = i - n0; }
        else                  { s = (const float4*)W2; d = (ushort4*)w2b; j = i - n0 - n1; }
        float4 v = s[j];
        ushort4 o;
        o.x = f2h_bits(v.x); o.y = f2h_bits(v.y);
        o.z = f2h_bits(v.z); o.w = f2h_bits(v.w);
        d[j] = o;
    }
}

// ---------------- scan: offsets + 64-row tile list + per-block bases ----------
__global__ void scan_k(const int* __restrict__ blkhist, int* __restrict__ offsets,
                       int* __restrict__ blkbase, int* __restrict__ meta,
                       int* __restrict__ tp, int* __restrict__ tm) {
    __shared__ int tot[NPLANES];
    const int t = threadIdx.x;
    if (t < NPLANES) {
        int s = 0;
#pragma unroll 8
        for (int b = 0; b < NBLK; ++b) s += blkhist[b * NPLANES + t];
        tot[t] = s;
    }
    __syncthreads();
    if (t == 0) {
        int off = 0, tc = 0;
        for (int p = 0; p < NPLANES; ++p) {
            offsets[p] = off;
            for (int m = 0; m < tot[p]; m += 64) { tp[tc] = p; tm[tc] = m; ++tc; }
            off += tot[p];
        }
        offsets[NPLANES] = off;
        meta[0] = tc;
    }
    __syncthreads();
    if (t < NPLANES) {
        int run = offsets[t];
#pragma unroll 8
        for (int b = 0; b < NBLK; ++b) {
            blkbase[b * NPLANES + t] = run;
            run += blkhist[b * NPLANES + t];
        }
    }
}

__global__ void scatter_k(const int* __restrict__ pidx, const int* __restrict__ blkbase,
                          int* __restrict__ perm) {
    __shared__ int wcnt[4][NPLANES];
    __shared__ int wbase[4][NPLANES];
    const int t = threadIdx.x, lane = t & 63, wave = t >> 6;
    const int i = blockIdx.x * 256 + t;
    const int p = pidx[i];
    int rank = 0;
#pragma unroll
    for (int q = 0; q < NPLANES; ++q) {
        unsigned long long m = __ballot(p == q);
        if (lane == 0) wcnt[wave][q] = __popcll(m);
        if (p == q) rank = __popcll(m & ((1ULL << lane) - 1));
    }
    __syncthreads();
    if (t < NPLANES) {
        int run = blkbase[blockIdx.x * NPLANES + t];
#pragma unroll
        for (int w = 0; w < 4; ++w) { wbase[w][t] = run; run += wcnt[w][t]; }
    }
    __syncthreads();
    perm[wbase[wave][p] + rank] = i;
}

// XCD-chunked tile mapping: all NSPLIT n-blocks of a tile on ONE XCD,
// tiles chunked contiguously per XCD (m204 bijective) so W[p] stays L2-hot.
// VERIFIED R6: HW round-robin XCD = linear_block_id % 8 (FETCH 68.6->11.1 MB).
#define XCD_MAP(NSPLIT)                                                        \
    const int ntiles = meta[0];                                                \
    const int xcd = blockIdx.x & 7, idx = blockIdx.x >> 3;                     \
    const int q8 = ntiles >> 3, r8 = ntiles & 7;                               \
    const int tn = q8 + (xcd < r8 ? 1 : 0);                                    \
    if (idx >= tn * (NSPLIT)) return;                                          \
    const int tile = (xcd < r8 ? xcd * (q8 + 1)                                \
                               : r8 * (q8 + 1) + (xcd - r8) * q8)              \
                     + idx / (NSPLIT);                                         \
    const int n0v = (idx % (NSPLIT)) * 128;

// ---------------- gemm1: 64x128 tile, BK=64, A via perm, LDS-staged epilogue
// (exact R7 config: best measured 45.7 us)
__global__ __launch_bounds__(256, 6) void gemm1_k(
    const u16* __restrict__ xb, const u16* __restrict__ w1b,
    const float* __restrict__ b1, const int* __restrict__ perm,
    const int* __restrict__ offsets, const int* __restrict__ meta,
    const int* __restrict__ tp, const int* __restrict__ tm,
    u16* __restrict__ hb)
{
    __shared__ __align__(16) u16 smem[12288];   // sA 8KB | sB 16KB; sOut 16KB reuse
    XCD_MAP(8)
    const int p   = tp[tile];
    const int m0  = tm[tile];
    const int off = offsets[p];
    const int cnt = offsets[p + 1] - off;

    u16* const sA = smem;
    u16* const sB = smem + 4096;

    const int tid = threadIdx.x;
    const u16* aptr[2];
    const u16* bptr[4];
#pragma unroll
    for (int c = 0; c < 2; ++c) {
        const int slot = c * 256 + tid, row = slot >> 3, ch = slot & 7;
        const int gr = min(m0 + row, cnt - 1);
        aptr[c] = xb + (size_t)perm[off + gr] * DIN + ((ch ^ (row & 7)) * 8);
    }
#pragma unroll
    for (int c = 0; c < 4; ++c) {
        const int slot = c * 256 + tid, row = slot >> 3, ch = slot & 7;
        bptr[c] = w1b + ((size_t)p * DHID + n0v + row) * DIN + ((ch ^ (row & 7)) * 8);
    }
    const int wave = tid >> 6, lane = tid & 63;
    const int wr = wave >> 1, wc = wave & 1;    // 2x2 waves, wave tile 32x64
    const int lm = lane & 15, lk = lane >> 4;

    f32x4 acc[2][4];
#pragma unroll
    for (int a = 0; a < 2; ++a)
#pragma unroll
        for (int b = 0; b < 4; ++b) acc[a][b] = (f32x4){0.f, 0.f, 0.f, 0.f};

    for (int kt = 0; kt < DIN / 64; ++kt) {
        const int k0 = kt * 64;
#pragma unroll
        for (int c = 0; c < 2; ++c) gl_lds16(aptr[c] + k0, sA + c * 2048 + tid * 8);
#pragma unroll
        for (int c = 0; c < 4; ++c) gl_lds16(bptr[c] + k0, sB + c * 2048 + tid * 8);
        __syncthreads();
#pragma unroll
        for (int kk = 0; kk < 2; ++kk) {
            f16x8 af[2], bf[4];
#pragma unroll
            for (int mf = 0; mf < 2; ++mf) {
                const int row = wr * 32 + mf * 16 + lm;
                const int g   = kk * 4 + lk;
                af[mf] = *(const f16x8*)(sA + row * 64 + ((g ^ (row & 7)) * 8));
            }
#pragma unroll
            for (int nf = 0; nf < 4; ++nf) {
                const int row = wc * 64 + nf * 16 + lm;
                const int g   = kk * 4 + lk;
                bf[nf] = *(const f16x8*)(sB + row * 64 + ((g ^ (row & 7)) * 8));
            }
#pragma unroll
            for (int mf = 0; mf < 2; ++mf)
#pragma unroll
                for (int nf = 0; nf < 4; ++nf)
                    acc[mf][nf] = __builtin_amdgcn_mfma_f32_16x16x32_f16(
                        af[mf], bf[nf], acc[mf][nf], 0, 0, 0);
        }
        __syncthreads();
    }

    // ---- epilogue: fast gelu -> chunk-swizzled sOut, then coalesced copy-out ----
    u16* const sOut = smem;                     // 64 x 128 u16 = 16KB
#pragma unroll
    for (int nf = 0; nf < 4; ++nf) {
        const int col = wc * 64 + nf * 16 + lm;
        const float bb = b1[p * DHID + n0v + col];
        const int cc = col >> 3, c7 = col & 7;
#pragma unroll
        for (int mf = 0; mf < 2; ++mf) {
#pragma unroll
            for (int j = 0; j < 4; ++j) {
                const int tok = wr * 32 + mf * 16 + lk * 4 + j;
                sOut[tok * 128 + ((cc ^ (tok & 15)) * 8) + c7] =
                    f2h_bits(gelu_fast(acc[mf][nf][j] + bb));
            }
        }
    }
    __syncthreads();
    const int r = tid >> 2, qq = tid & 3;       // 4 threads/row, 64B each
    if (m0 + r < cnt) {
        u16* dst = hb + (size_t)(off + m0 + r) * DHID + n0v;
#pragma unroll
        for (int c = 0; c < 4; ++c) {
            const int l = qq * 4 + c;
            *(int4*)(dst + l * 8) = *(const int4*)(sOut + r * 128 + ((l ^ (r & 15)) * 8));
        }
    }
}

// ---------------- gemm2: 64x128 tile, BK=128 (KT=8, half the drains) ---------
// single-buffer: 48KB LDS -> 3 blocks/CU (matches measured residency anyway);
// 16-chunk rows, swizzle ch^(row&15) -> distinct chunks across 16 lanes (2-way, free)
__global__ __launch_bounds__(256, 3) void gemm2_k(
    const u16* __restrict__ hb, const u16* __restrict__ w2b,
    const float* __restrict__ b2, const int* __restrict__ perm,
    const int* __restrict__ offsets, const int* __restrict__ meta,
    const int* __restrict__ tp, const int* __restrict__ tm,
    float* __restrict__ out)
{
    __shared__ __align__(16) u16 smem[24576];   // sA 16KB | sB 32KB
    XCD_MAP(2)
    const int p   = tp[tile];
    const int m0  = tm[tile];
    const int off = offsets[p];
    const int cnt = offsets[p + 1] - off;

    u16* const sA = smem;
    u16* const sB = smem + 8192;

    const int tid = threadIdx.x;
    // A: 64 rows x 128K x 2B = 16KB = 1024 slots (16/row); 4 per thread
    const u16* aptr[4];
#pragma unroll
    for (int c = 0; c < 4; ++c) {
        const int slot = c * 256 + tid, row = slot >> 4, ch = slot & 15;
        aptr[c] = hb + (size_t)(off + min(m0 + row, cnt - 1)) * DHID + ((ch ^ (row & 15)) * 8);
    }
    // B: 128 rows x 128K x 2B = 32KB = 2048 slots; 8 per thread
    const u16* bptr[8];
#pragma unroll
    for (int c = 0; c < 8; ++c) {
        const int slot = c * 256 + tid, row = slot >> 4, ch = slot & 15;
        bptr[c] = w2b + ((size_t)p * DOUT + n0v + row) * DHID + ((ch ^ (row & 15)) * 8);
    }
    const int wave = tid >> 6, lane = tid & 63;
    const int wr = wave >> 1, wc = wave & 1;    // 2x2 waves, wave tile 32x64
    const int lm = lane & 15, lk = lane >> 4;

    f32x4 acc[2][4];
#pragma unroll
    for (int a = 0; a < 2; ++a)
#pragma unroll
        for (int b = 0; b < 4; ++b) acc[a][b] = (f32x4){0.f, 0.f, 0.f, 0.f};

    for (int kt = 0; kt < DHID / 128; ++kt) {   // 8 K-steps
        const int k0 = kt * 128;
#pragma unroll
        for (int c = 0; c < 4; ++c) gl_lds16(aptr[c] + k0, sA + c * 2048 + tid * 8);
#pragma unroll
        for (int c = 0; c < 8; ++c) gl_lds16(bptr[c] + k0, sB + c * 2048 + tid * 8);
        __syncthreads();
#pragma unroll
        for (int kk = 0; kk < 4; ++kk) {
            f16x8 af[2], bf[4];
#pragma unroll
            for (int mf = 0; mf < 2; ++mf) {
                const int row = wr * 32 + mf * 16 + lm;
                const int g   = kk * 4 + lk;
                af[mf] = *(const f16x8*)(sA + row * 128 + ((g ^ (row & 15)) * 8));
            }
#pragma unroll
            for (int nf = 0; nf < 4; ++nf) {
                const int row = wc * 64 + nf * 16 + lm;
                const int g   = kk * 4 + lk;
                bf[nf] = *(const f16x8*)(sB + row * 128 + ((g ^ (row & 15)) * 8));
            }
#pragma unroll
            for (int mf = 0; mf < 2; ++mf)
#pragma unroll
                for (int nf = 0; nf < 4; ++nf)
                    acc[mf][nf] = __builtin_amdgcn_mfma_f32_16x16x32_f16(
                        af[mf], bf[nf], acc[mf][nf], 0, 0, 0);
        }
        __syncthreads();
    }

    // epilogue: f32 scatter, 64B runs per 16-lane group
#pragma unroll
    for (int nf = 0; nf < 4; ++nf) {
        const int col = n0v + wc * 64 + nf * 16 + lm;
        const float bb = b2[p * DOUT + col];
#pragma unroll
        for (int mf = 0; mf < 2; ++mf) {
#pragma unroll
            for (int j = 0; j < 4; ++j) {
                const int tok = wr * 32 + mf * 16 + lk * 4 + j;
                if (m0 + tok < cnt)
                    out[(size_t)perm[off + m0 + tok] * DOUT + col] = acc[mf][nf][j] + bb;
            }
        }
    }
}

// ---------------- launch ----------------
extern "C" void kernel_launch(void* const* d_in, const int* in_sizes, int n_in,
                              void* d_out, int out_size, void* d_ws, size_t ws_size,
                              hipStream_t stream) {
    const float* x    = (const float*)d_in[0];
    const float* W1   = (const float*)d_in[1];
    const float* b1   = (const float*)d_in[2];
    const float* W2   = (const float*)d_in[3];
    const float* b2   = (const float*)d_in[4];
    const int*   pidx = (const int*)d_in[5];
    float*       out  = (float*)d_out;

    char* ws      = (char*)d_ws;
    int* offsets  = (int*)(ws + WS_OFFSETS);
    int* meta     = (int*)(ws + WS_META);
    int* tp       = (int*)(ws + WS_TP);
    int* tm       = (int*)(ws + WS_TM);
    int* blkhist  = (int*)(ws + WS_BLKHIST);
    int* blkbase  = (int*)(ws + WS_BLKBASE);
    int* perm     = (int*)(ws + WS_PERM);
    u16* xb       = (u16*)(ws + WS_XB);
    u16* w1b      = (u16*)(ws + WS_W1B);
    u16* w2b      = (u16*)(ws + WS_W2B);
    u16* hb       = (u16*)(ws + WS_HB);

    prep_k<<<2048, 256, 0, stream>>>(pidx, x, W1, W2, blkhist, xb, w1b, w2b);
    scan_k<<<1, 64, 0, stream>>>(blkhist, offsets, blkbase, meta, tp, tm);
    scatter_k<<<NBLK, 256, 0, stream>>>(pidx, blkbase, perm);

    // gemm1: 8 n-blocks/tile, <=66 tiles/xcd -> 8*66*8 = 4224 slots
    gemm1_k<<<4224, 256, 0, stream>>>(xb, w1b, b1, perm, offsets, meta, tp, tm, hb);
    // gemm2: 2 n-blocks/tile -> 8*66*2 = 1056 slots
    gemm2_k<<<1056, 256, 0, stream>>>(hb, w2b, b2, perm, offsets, meta, tp, tm, out);
}